// Round 1
// baseline (333.915 us; speedup 1.0000x reference)
//
#include <hip/hip_runtime.h>

// ---------------------------------------------------------------------------
// QuaternionLinear == one GEMM: out[M=32768][N=1024] = x[M][K=1024] * W^T + b
// where W[4o+co][4i+ci] = sign(co,ci) * weight_{comp(co,ci)}[o][i].
// Strategy: (1) cvt x fp32->bf16 into ws, (2) build combined bf16 W (B^T
// layout) in ws, (3) m97-style bf16 MFMA GEMM (128x128 tile, BK=32,
// global_load_lds width=16), fp32 accumulate, bias fused in epilogue.
// ---------------------------------------------------------------------------

typedef __attribute__((ext_vector_type(8))) short bf16x8;   // 8 bf16 = 4 VGPRs
typedef __attribute__((ext_vector_type(4))) float f32x4;

#define M_TOT 32768
#define N_TOT 1024
#define K_TOT 1024
#define BM 128
#define BN 128
#define BK 32

__device__ __forceinline__ unsigned short f2bf(float f) {
    union { float f; unsigned int u; } v; v.f = f;
    unsigned int u = v.u;
    u += 0x7fffu + ((u >> 16) & 1u);   // round-to-nearest-even
    return (unsigned short)(u >> 16);
}

// ---- kernel 1: x fp32 -> bf16 (vectorized: 16B read, 8B write per lane) ----
__global__ __launch_bounds__(256) void cvt_x(const float4* __restrict__ x,
                                             ushort4* __restrict__ y) {
    int idx = blockIdx.x * 256 + threadIdx.x;   // exact: no bounds needed
    float4 a = x[idx];
    ushort4 o;
    o.x = f2bf(a.x); o.y = f2bf(a.y); o.z = f2bf(a.z); o.w = f2bf(a.w);
    y[idx] = o;
}

// ---- kernel 2: combined quaternion weight matrix, bf16, [N][K] (B^T) ------
__constant__ int   c_widx[16] = {0,1,2,3, 1,0,3,2, 2,3,0,1, 3,2,1,0};
__constant__ float c_sign[16] = {1.f,-1.f,-1.f,-1.f,
                                 1.f, 1.f, 1.f,-1.f,
                                 1.f,-1.f, 1.f, 1.f,
                                 1.f, 1.f,-1.f, 1.f};

__global__ __launch_bounds__(256) void build_w(const float* __restrict__ R,
                                               const float* __restrict__ I,
                                               const float* __restrict__ J,
                                               const float* __restrict__ Kw,
                                               unsigned short* __restrict__ Wb) {
    int idx = blockIdx.x * 256 + threadIdx.x;   // over [n][k], 1M elems
    int n = idx >> 10, k = idx & 1023;
    int o = n >> 2, co = n & 3;
    int i = k >> 2, ci = k & 3;
    const float* ws[4] = {R, I, J, Kw};
    int t = co * 4 + ci;
    float v = ws[c_widx[t]][o * 256 + i] * c_sign[t];
    Wb[idx] = f2bf(v);
}

// ---- kernel 3: bf16 MFMA GEMM, B^T layout, fp32 out + bias ----------------
__device__ __forceinline__ void async_lds16(const void* g, void* l) {
    __builtin_amdgcn_global_load_lds(
        (const __attribute__((address_space(1))) unsigned int*)g,
        (__attribute__((address_space(3))) unsigned int*)l,
        16, 0, 0);
}

__global__ __launch_bounds__(256) void gemm_bt(
        const unsigned short* __restrict__ A,   // [M][K] bf16
        const unsigned short* __restrict__ B,   // [N][K] bf16
        const float* __restrict__ bias,         // [N]
        float* __restrict__ C) {                // [M][N] fp32
    __shared__ unsigned short As[BM * BK];      // row-major [128][32], 8 KiB
    __shared__ unsigned short Bs[BN * BK];      // row-major [128][32], 8 KiB

    const int tid  = threadIdx.x;
    const int wave = tid >> 6;
    const int lane = tid & 63;
    const int quad = lane >> 4;     // 0..3
    const int r16  = lane & 15;     // 0..15
    const int wm   = wave & 1;      // wave grid 2x2, each wave 64x64
    const int wn   = wave >> 1;

    const int m0 = blockIdx.x * BM;
    const int n0 = blockIdx.y * BN;

    f32x4 acc[4][4];
#pragma unroll
    for (int i = 0; i < 4; ++i)
#pragma unroll
        for (int j = 0; j < 4; ++j)
            acc[i][j] = (f32x4){0.f, 0.f, 0.f, 0.f};

    // staging geometry: one wave instruction moves 64 lanes x 16 B = 1024 B
    // = 16 rows x 32 bf16.  LDS dest is wave-uniform base + lane*16, so the
    // LDS tile is unpadded row-major and lane l points at row l/4, col (l%4)*8.
    const int srow = lane >> 2;          // 0..15 within a 16-row chunk
    const int scol = (lane & 3) * 8;     // bf16 column

    for (int k0 = 0; k0 < K_TOT; k0 += BK) {
        __syncthreads();                 // LDS reuse from previous iter
#pragma unroll
        for (int j = 0; j < 2; ++j) {
            int q   = wave * 2 + j;      // chunk 0..7
            int row = q * 16 + srow;
            async_lds16(A + (size_t)(m0 + row) * K_TOT + k0 + scol, As + q * 512);
            async_lds16(B + (size_t)(n0 + row) * K_TOT + k0 + scol, Bs + q * 512);
        }
        __syncthreads();                 // drains vmcnt(0): staging visible

        bf16x8 af[4], bf[4];
#pragma unroll
        for (int i = 0; i < 4; ++i) {
            // A-operand layout: A[m = lane&15][k = quad*8 + j]
            af[i] = *(const bf16x8*)(As + (wm * 64 + i * 16 + r16) * BK + quad * 8);
            bf[i] = *(const bf16x8*)(Bs + (wn * 64 + i * 16 + r16) * BK + quad * 8);
        }
#pragma unroll
        for (int i = 0; i < 4; ++i)
#pragma unroll
            for (int j = 0; j < 4; ++j)
                acc[i][j] = __builtin_amdgcn_mfma_f32_16x16x32_bf16(
                    af[i], bf[j], acc[i][j], 0, 0, 0);
    }

    // epilogue: C/D layout col = lane&15 (N), row = quad*4 + reg (M)
#pragma unroll
    for (int j = 0; j < 4; ++j) {
        int col  = n0 + wn * 64 + j * 16 + r16;
        float bv = bias[col];
#pragma unroll
        for (int i = 0; i < 4; ++i) {
            int rowb = m0 + wm * 64 + i * 16 + quad * 4;
            f32x4 v  = acc[i][j];
#pragma unroll
            for (int r = 0; r < 4; ++r)
                C[(size_t)(rowb + r) * N_TOT + col] = v[r] + bv;
        }
    }
}

extern "C" void kernel_launch(void* const* d_in, const int* in_sizes, int n_in,
                              void* d_out, int out_size, void* d_ws, size_t ws_size,
                              hipStream_t stream) {
    const float* x    = (const float*)d_in[0];   // [4, 8192, 1024]
    const float* rw   = (const float*)d_in[1];   // [256, 256]
    const float* iw   = (const float*)d_in[2];
    const float* jw   = (const float*)d_in[3];
    const float* kw   = (const float*)d_in[4];
    const float* bias = (const float*)d_in[5];   // [1024]
    float* out = (float*)d_out;                  // [4, 8192, 1024]

    // workspace: [0, 64 MiB) x in bf16; [64 MiB, 66 MiB) combined W in bf16
    unsigned short* xb = (unsigned short*)d_ws;
    unsigned short* Wb = (unsigned short*)((char*)d_ws + (size_t)M_TOT * K_TOT * 2);

    // 1) convert x -> bf16 (33.5M elems, 4/thread)
    cvt_x<<<(M_TOT * (size_t)K_TOT) / 4 / 256, 256, 0, stream>>>(
        (const float4*)x, (ushort4*)xb);

    // 2) build combined 1024x1024 bf16 weight (B^T layout)
    build_w<<<(N_TOT * K_TOT) / 256, 256, 0, stream>>>(rw, iw, jw, kw, Wb);

    // 3) GEMM: 256 x 8 tiles of 128x128
    dim3 grid(M_TOT / BM, N_TOT / BN);
    gemm_bt<<<grid, 256, 0, stream>>>(xb, Wb, bias, out);
}

// Round 3
// 329.244 us; speedup vs baseline: 1.0142x; 1.0142x over previous
//
#include <hip/hip_runtime.h>

// ---------------------------------------------------------------------------
// QuaternionLinear == one GEMM: out[M=32768][N=1024] = x[M][K=1024] * W^T + b
// where W[4o+co][4i+ci] = sign(co,ci) * weight_{comp(co,ci)}[o][i].
// (1) cvt x fp32->bf16 into ws, (2) build combined bf16 W (B^T layout,
// branchless/scratch-free), (3) m97-style bf16 MFMA GEMM (128x128 tile,
// BK=32, global_load_lds width=16), fp32 accumulate, bias fused in epilogue.
// ---------------------------------------------------------------------------

typedef __attribute__((ext_vector_type(8))) short bf16x8;   // 8 bf16 = 4 VGPRs
typedef __attribute__((ext_vector_type(4))) float f32x4;

#define M_TOT 32768
#define N_TOT 1024
#define K_TOT 1024
#define BM 128
#define BN 128
#define BK 32

__device__ __forceinline__ unsigned short f2bf(float f) {
    union { float f; unsigned int u; } v; v.f = f;
    unsigned int u = v.u;
    u += 0x7fffu + ((u >> 16) & 1u);   // round-to-nearest-even
    return (unsigned short)(u >> 16);
}

// ---- kernel 1: x fp32 -> bf16 (16B read, 8B write per lane) ---------------
__global__ __launch_bounds__(256) void cvt_x(const float4* __restrict__ x,
                                             ushort4* __restrict__ y) {
    int idx = blockIdx.x * 256 + threadIdx.x;   // exact: no bounds needed
    float4 a = x[idx];
    ushort4 o;
    o.x = f2bf(a.x); o.y = f2bf(a.y); o.z = f2bf(a.z); o.w = f2bf(a.w);
    y[idx] = o;
}

// ---- kernel 2: combined quaternion weight matrix, bf16, [N][K] (B^T) ------
// One block per output row n: co = n&3 is block-uniform -> scalar branch,
// no dynamic-indexed private array (that spilled to scratch).
// Row contents (ci = 0..3):
//   co=0: [ r, -i, -j, -k]
//   co=1: [ i,  r,  k, -j]
//   co=2: [ j, -k,  r,  i]
//   co=3: [ k,  j, -i,  r]
__global__ __launch_bounds__(256) void build_w(const float* __restrict__ R,
                                               const float* __restrict__ I,
                                               const float* __restrict__ J,
                                               const float* __restrict__ Kw,
                                               ushort4* __restrict__ Wb) {
    int n = blockIdx.x;          // 0..1023 (output row of W)
    int i = threadIdx.x;         // 0..255  (input quaternion index)
    int o = n >> 2, co = n & 3;
    int base = o * 256 + i;
    float r = R[base], ii = I[base], j = J[base], k = Kw[base];
    float v0, v1, v2, v3;
    if (co == 0)      { v0 = r;  v1 = -ii; v2 = -j;  v3 = -k; }
    else if (co == 1) { v0 = ii; v1 = r;   v2 = k;   v3 = -j; }
    else if (co == 2) { v0 = j;  v1 = -k;  v2 = r;   v3 = ii; }
    else              { v0 = k;  v1 = j;   v2 = -ii; v3 = r;  }
    ushort4 w;
    w.x = f2bf(v0); w.y = f2bf(v1); w.z = f2bf(v2); w.w = f2bf(v3);
    Wb[n * 256 + i] = w;         // coalesced 8B/lane
}

// ---- kernel 3: bf16 MFMA GEMM, B^T layout, fp32 out + bias ----------------
__device__ __forceinline__ void async_lds16(const void* g, void* l) {
    __builtin_amdgcn_global_load_lds(
        (const __attribute__((address_space(1))) unsigned int*)g,
        (__attribute__((address_space(3))) unsigned int*)l,
        16, 0, 0);
}

__global__ __launch_bounds__(256) void gemm_bt(
        const unsigned short* __restrict__ A,   // [M][K] bf16
        const unsigned short* __restrict__ B,   // [N][K] bf16
        const float* __restrict__ bias,         // [N]
        float* __restrict__ C) {                // [M][N] fp32
    __shared__ unsigned short As[BM * BK];      // row-major [128][32], 8 KiB
    __shared__ unsigned short Bs[BN * BK];      // row-major [128][32], 8 KiB

    const int tid  = threadIdx.x;
    const int wave = tid >> 6;
    const int lane = tid & 63;
    const int quad = lane >> 4;     // 0..3
    const int r16  = lane & 15;     // 0..15
    const int wm   = wave & 1;      // wave grid 2x2, each wave 64x64
    const int wn   = wave >> 1;

    const int m0 = blockIdx.x * BM;
    const int n0 = blockIdx.y * BN;

    f32x4 acc[4][4];
#pragma unroll
    for (int i = 0; i < 4; ++i)
#pragma unroll
        for (int j = 0; j < 4; ++j)
            acc[i][j] = (f32x4){0.f, 0.f, 0.f, 0.f};

    // staging geometry: one wave instruction moves 64 lanes x 16 B = 1024 B
    // = 16 rows x 32 bf16.  LDS dest is wave-uniform base + lane*16, so the
    // LDS tile is unpadded row-major; lane l covers row l/4, col (l%4)*8.
    const int srow = lane >> 2;          // 0..15 within a 16-row chunk
    const int scol = (lane & 3) * 8;     // bf16 column

    for (int k0 = 0; k0 < K_TOT; k0 += BK) {
        __syncthreads();                 // LDS reuse from previous iter
#pragma unroll
        for (int j = 0; j < 2; ++j) {
            int q   = wave * 2 + j;      // chunk 0..7
            int row = q * 16 + srow;
            async_lds16(A + (size_t)(m0 + row) * K_TOT + k0 + scol, As + q * 512);
            async_lds16(B + (size_t)(n0 + row) * K_TOT + k0 + scol, Bs + q * 512);
        }
        __syncthreads();                 // drains vmcnt(0): staging visible

        bf16x8 af[4], bf[4];
#pragma unroll
        for (int i = 0; i < 4; ++i) {
            // A-operand layout: A[m = lane&15][k = quad*8 + j]
            af[i] = *(const bf16x8*)(As + (wm * 64 + i * 16 + r16) * BK + quad * 8);
            bf[i] = *(const bf16x8*)(Bs + (wn * 64 + i * 16 + r16) * BK + quad * 8);
        }
#pragma unroll
        for (int i = 0; i < 4; ++i)
#pragma unroll
            for (int j = 0; j < 4; ++j)
                acc[i][j] = __builtin_amdgcn_mfma_f32_16x16x32_bf16(
                    af[i], bf[j], acc[i][j], 0, 0, 0);
    }

    // epilogue: C/D layout col = lane&15 (N), row = quad*4 + reg (M)
#pragma unroll
    for (int j = 0; j < 4; ++j) {
        int col  = n0 + wn * 64 + j * 16 + r16;
        float bv = bias[col];
#pragma unroll
        for (int i = 0; i < 4; ++i) {
            int rowb = m0 + wm * 64 + i * 16 + quad * 4;
            f32x4 v  = acc[i][j];
#pragma unroll
            for (int r = 0; r < 4; ++r)
                C[(size_t)(rowb + r) * N_TOT + col] = v[r] + bv;
        }
    }
}

extern "C" void kernel_launch(void* const* d_in, const int* in_sizes, int n_in,
                              void* d_out, int out_size, void* d_ws, size_t ws_size,
                              hipStream_t stream) {
    const float* x    = (const float*)d_in[0];   // [4, 8192, 1024]
    const float* rw   = (const float*)d_in[1];   // [256, 256]
    const float* iw   = (const float*)d_in[2];
    const float* jw   = (const float*)d_in[3];
    const float* kw   = (const float*)d_in[4];
    const float* bias = (const float*)d_in[5];   // [1024]
    float* out = (float*)d_out;                  // [4, 8192, 1024]

    // workspace: [0, 64 MiB) x in bf16; [64 MiB, 66 MiB) combined W in bf16
    unsigned short* xb = (unsigned short*)d_ws;
    unsigned short* Wb = (unsigned short*)((char*)d_ws + (size_t)M_TOT * K_TOT * 2);

    // 1) convert x -> bf16 (33.5M elems, 4/thread)
    cvt_x<<<(M_TOT * (size_t)K_TOT) / 4 / 256, 256, 0, stream>>>(
        (const float4*)x, (ushort4*)xb);

    // 2) build combined 1024x1024 bf16 weight (B^T layout), 1 block/row
    build_w<<<N_TOT, 256, 0, stream>>>(rw, iw, jw, kw, (ushort4*)Wb);

    // 3) GEMM: 256 x 8 tiles of 128x128
    dim3 grid(M_TOT / BM, N_TOT / BN);
    gemm_bt<<<grid, 256, 0, stream>>>(xb, Wb, bias, out);
}